// Round 8
// baseline (275.094 us; speedup 1.0000x reference)
//
#include <hip/hip_runtime.h>
#include <hip/hip_fp16.h>
#include <math.h>

typedef _Float16 half8_t __attribute__((ext_vector_type(8)));
typedef float f32x4 __attribute__((ext_vector_type(4)));

struct __align__(16) h2x4 { __half2 a, b, c, d; };

// Edge access: flag=1 -> int64 storage, flag=0 -> int32.
__device__ inline int edge_src(const int* ew, int f, int e, int E) {
    return f ? ew[2 * e] : ew[e];
}
__device__ inline int edge_dst(const int* ew, int f, int e, int E) {
    return f ? ew[2 * E + 2 * e] : ew[E + e];
}

// ---------------- edge dtype sniff + bsize zero ----------------
__global__ void k_detect(const int* __restrict__ ew, int* __restrict__ flag,
                         int* __restrict__ bsize) {
    __shared__ int nz;
    if (threadIdx.x == 0) nz = 0;
    bsize[threadIdx.x] = 0;
    __syncthreads();
    int a = ew[2 * threadIdx.x + 1];
    int b = ew[512 + 2 * threadIdx.x + 1];
    if (a | b) atomicAdd(&nz, 1);
    __syncthreads();
    if (threadIdx.x == 0) *flag = (nz == 0) ? 1 : 0;
}

// ---------------- bucketed CSR build (buckets of 256 dst nodes, NB<=256) ----------------
__global__ __launch_bounds__(256) void k_bhist(const int* __restrict__ ew,
                                               const int* __restrict__ flag,
                                               int* __restrict__ bsize,
                                               int E, int NB, int chunk) {
    __shared__ int hist[256];
    int t = threadIdx.x;
    hist[t] = 0;
    __syncthreads();
    int f = *flag;
    int c0 = blockIdx.x * chunk, c1 = min(E, c0 + chunk);
    for (int e = c0 + t; e < c1; e += 256)
        atomicAdd(&hist[edge_dst(ew, f, e, E) >> 8], 1);
    __syncthreads();
    if (t < NB && hist[t]) atomicAdd(&bsize[t], hist[t]);
}

// scan bucket sizes; also zero the BN stat accumulators (saves 2 memsets)
__global__ __launch_bounds__(256) void k_bscan(const int* __restrict__ bsize,
                                               int* __restrict__ bbase,
                                               int* __restrict__ bcur, int NB,
                                               float* __restrict__ S1,
                                               float* __restrict__ S2) {
    __shared__ int buf[256];
    int t = threadIdx.x;
    S1[t] = 0.f;
    S2[t] = 0.f;
    int v = (t < NB) ? bsize[t] : 0;
    buf[t] = v;
    __syncthreads();
    int x = v;
    for (int off = 1; off < 256; off <<= 1) {
        int y = (t >= off) ? buf[t - off] : 0;
        __syncthreads();
        x += y;
        buf[t] = x;
        __syncthreads();
    }
    if (t <= NB) {
        int ex = (t < NB) ? (buf[t] - bsize[t]) : buf[NB ? NB - 1 : 0];
        bbase[t] = ex;
        if (t < NB) bcur[t] = ex;
    }
}

__global__ __launch_bounds__(256) void k_part(const int* __restrict__ ew,
                                              const int* __restrict__ flag,
                                              int* __restrict__ bcur,
                                              int2* __restrict__ be,
                                              int E, int NB, int chunk) {
    __shared__ int histL[256], baseL[256];
    int t = threadIdx.x;
    histL[t] = 0;
    __syncthreads();
    int f = *flag;
    int c0 = blockIdx.x * chunk, c1 = min(E, c0 + chunk);
    for (int e = c0 + t; e < c1; e += 256)
        atomicAdd(&histL[edge_dst(ew, f, e, E) >> 8], 1);
    __syncthreads();
    if (t < NB) {
        int h = histL[t];
        baseL[t] = h ? atomicAdd(&bcur[t], h) : 0;
    }
    __syncthreads();
    histL[t] = 0;
    __syncthreads();
    for (int e = c0 + t; e < c1; e += 256) {
        int s = edge_src(ew, f, e, E);
        int d = edge_dst(ew, f, e, E);
        int b = d >> 8;
        int off = baseL[b] + atomicAdd(&histL[b], 1);
        be[off] = make_int2(s, d);
    }
}

// per-bucket: degree count + scan -> rp/dinv, then fill col (merged)
__global__ __launch_bounds__(256) void k_bdegfill(const int2* __restrict__ be,
                                                  const int* __restrict__ bbase,
                                                  int* __restrict__ rp,
                                                  float* __restrict__ dinv,
                                                  int* __restrict__ col,
                                                  int N, int NB) {
    __shared__ int cnt[256];
    __shared__ int buf[256];
    int t = threadIdx.x, b = blockIdx.x;
    cnt[t] = 0;
    __syncthreads();
    int p0 = bbase[b], p1 = bbase[b + 1];
    for (int p = p0 + t; p < p1; p += 256)
        atomicAdd(&cnt[be[p].y & 255], 1);
    __syncthreads();
    int v = cnt[t];
    buf[t] = v;
    __syncthreads();
    int x = v;
    for (int off = 1; off < 256; off <<= 1) {
        int y = (t >= off) ? buf[t - off] : 0;
        __syncthreads();
        x += y;
        buf[t] = x;
        __syncthreads();
    }
    int start = bbase[b] + x - v;   // exclusive prefix within bucket
    int i = (b << 8) + t;
    if (i < N) {
        rp[i] = start;
        dinv[i] = rsqrtf((float)(v + 1));  // +1 self loop
    }
    if (b == NB - 1 && t == 255) rp[N] = bbase[b] + x;  // = E
    __syncthreads();
    cnt[t] = start;                 // becomes write cursor
    __syncthreads();
    for (int p = p0 + t; p < p1; p += 256) {
        int2 e = be[p];
        int pos = atomicAdd(&cnt[e.y & 255], 1);
        col[pos] = e.x;             // src (< 2^16 not required here; full int)
    }
}

// ------- MFMA matmul: H = fp16( dinv[r] * act(X) @ W ) -------
// PIN: input is f16 plane-major [f/16][node][16]; else row-major (f32 if XF32)
// POUT: output plane-major; else row-major f16
template <int D, bool FUSE, bool XF32, bool PIN, bool POUT>
__global__ __launch_bounds__(256) void k_mmf(const void* __restrict__ Xv,
                                             const float* __restrict__ W,
                                             __half* __restrict__ H,
                                             const float* __restrict__ dinv,
                                             const float* __restrict__ S,
                                             const float* __restrict__ g,
                                             const float* __restrict__ be_,
                                             int N, float invN) {
    constexpr int NF = D / 16;
    __shared__ _Float16 sW[4][NF][4][16][8];
    __shared__ float sAl[128], sBe[128];
    const int t = threadIdx.x;
    if (FUSE && t < 128) {
        float m = S[t] * invN;
        float var = fmaf(-m, m, S[128 + t] * invN);
        float al = g[t] * rsqrtf(var + 1e-5f);
        sAl[t] = al;
        sBe[t] = fmaf(-m, al, be_[t]);
    }
    for (int idx = t; idx < 128 * D / 4; idx += 256) {
        int k = idx / (D / 4);
        int n4 = (idx % (D / 4)) * 4;
        float4 w4 = reinterpret_cast<const float4*>(W)[idx];
        int kb = k >> 5, kg = (k >> 3) & 3, j = k & 7;
        const float* wp = &w4.x;
#pragma unroll
        for (int jj = 0; jj < 4; jj++) {
            int n = n4 + jj;
            sW[kb][n >> 4][kg][n & 15][j] = (_Float16)wp[jj];
        }
    }
    __syncthreads();

    const int l = t & 63;
    const int w = t >> 6;
    const int row_base = blockIdx.x * 64 + w * 16;
    const int m16 = l & 15, kg = l >> 4;

    f32x4 acc[NF];
#pragma unroll
    for (int nf = 0; nf < NF; nf++) acc[nf] = (f32x4){0.f, 0.f, 0.f, 0.f};

    int ra = row_base + m16;
    if (ra > N - 1) ra = N - 1;

#pragma unroll
    for (int kb = 0; kb < 4; kb++) {
        int kbase = kb * 32 + kg * 8;
        half8_t a;
        if (XF32) {
            const float* Xf = (const float*)Xv;
            float4 x0 = reinterpret_cast<const float4*>(Xf + (size_t)ra * 128 + kbase)[0];
            float4 x1 = reinterpret_cast<const float4*>(Xf + (size_t)ra * 128 + kbase)[1];
            a[0] = (_Float16)x0.x; a[1] = (_Float16)x0.y;
            a[2] = (_Float16)x0.z; a[3] = (_Float16)x0.w;
            a[4] = (_Float16)x1.x; a[5] = (_Float16)x1.y;
            a[6] = (_Float16)x1.z; a[7] = (_Float16)x1.w;
        } else {
            const __half* Xh = (const __half*)Xv;
            if (PIN) {
                // plane = kbase>>4, offset = kbase&15 (0 or 8)
                a = *reinterpret_cast<const half8_t*>(
                        Xh + (size_t)(kbase >> 4) * N * 16 + (size_t)ra * 16 + (kbase & 15));
            } else {
                a = *reinterpret_cast<const half8_t*>(Xh + (size_t)ra * 128 + kbase);
            }
            if (FUSE) {
                float4 al0 = *reinterpret_cast<const float4*>(&sAl[kbase]);
                float4 al1 = *reinterpret_cast<const float4*>(&sAl[kbase + 4]);
                float4 be0 = *reinterpret_cast<const float4*>(&sBe[kbase]);
                float4 be1 = *reinterpret_cast<const float4*>(&sBe[kbase + 4]);
                const float* alp0 = &al0.x; const float* alp1 = &al1.x;
                const float* bep0 = &be0.x; const float* bep1 = &be1.x;
#pragma unroll
                for (int j = 0; j < 4; j++)
                    a[j] = (_Float16)fmaxf(0.f, fmaf(alp0[j], (float)a[j], bep0[j]));
#pragma unroll
                for (int j = 0; j < 4; j++)
                    a[4 + j] = (_Float16)fmaxf(0.f, fmaf(alp1[j], (float)a[4 + j], bep1[j]));
            }
        }
#pragma unroll
        for (int nf = 0; nf < NF; nf++) {
            half8_t b = *reinterpret_cast<const half8_t*>(&sW[kb][nf][kg][m16][0]);
            acc[nf] = __builtin_amdgcn_mfma_f32_16x16x32_f16(a, b, acc[nf], 0, 0, 0);
        }
    }

    float dv[4];
    int rbase = row_base + kg * 4;
#pragma unroll
    for (int r = 0; r < 4; r++)
        dv[r] = (rbase + r < N) ? dinv[rbase + r] : 0.f;
#pragma unroll
    for (int nf = 0; nf < NF; nf++) {
#pragma unroll
        for (int r = 0; r < 4; r++) {
            int gr = rbase + r;
            if (gr < N) {
                __half val = __float2half(acc[nf][r] * dv[r]);
                if (POUT)
                    H[(size_t)nf * N * 16 + (size_t)gr * 16 + m16] = val;
                else
                    H[(size_t)gr * D + nf * 16 + m16] = val;
            }
        }
    }
}

// ------- column-split agg D=128: plane g on XCD g (g = bid%8), L2-resident gather -------
// block: 256 thr = 32 nodes x 8 lanes; lane j handles half2 feature pair 2j of plane g
__global__ __launch_bounds__(256) void k_aggp(const __half* __restrict__ Hp,
                                              const int* __restrict__ rp,
                                              const int* __restrict__ col,
                                              const float* __restrict__ dinv,
                                              const float* __restrict__ bias,
                                              __half* __restrict__ Tp, int N) {
    const int gG = blockIdx.x & 7;
    const int chunk = blockIdx.x >> 3;
    const __half* P = Hp + (size_t)gG * N * 16;
    __half* O = Tp + (size_t)gG * N * 16;
    const int t = threadIdx.x;
    const int j = t & 7;
    const int i = chunk * 32 + (t >> 3);
    if (i >= N) return;
    int e0 = rp[i], e1 = rp[i + 1];
    float di = dinv[i];
    float2 a = __half22float2(*reinterpret_cast<const __half2*>(P + (size_t)i * 16 + 2 * j));
    for (int e = e0; e < e1; e += 16) {
        float2 v[16];
#pragma unroll
        for (int u = 0; u < 16; u++) {
            int idx = e + u;
            bool ok = idx < e1;
            int s = col[ok ? idx : e0];
            float2 f = __half22float2(*reinterpret_cast<const __half2*>(P + (size_t)s * 16 + 2 * j));
            v[u].x = ok ? f.x : 0.f;
            v[u].y = ok ? f.y : 0.f;
        }
#pragma unroll
        for (int st = 1; st < 16; st <<= 1)
#pragma unroll
            for (int u = 0; u < 16; u += 2 * st) {
                v[u].x += v[u + st].x;
                v[u].y += v[u + st].y;
            }
        a.x += v[0].x;
        a.y += v[0].y;
    }
    float2 b = reinterpret_cast<const float2*>(bias)[gG * 8 + j];
    *reinterpret_cast<__half2*>(O + (size_t)i * 16 + 2 * j) =
        __floats2half2_rn(fmaf(di, a.x, b.x), fmaf(di, a.y, b.y));
}

// ------- agg D=64: half-wave per node, row-major gather, f32 output -------
__global__ __launch_bounds__(256) void k_agg64(const __half2* __restrict__ Hs,
                                               const int* __restrict__ rp,
                                               const int* __restrict__ col,
                                               const float* __restrict__ dinv,
                                               const float* __restrict__ bias,
                                               float* __restrict__ out, int N) {
    int sub = threadIdx.x & 31;
    int i = blockIdx.x * 8 + (threadIdx.x >> 5);
    if (i >= N) return;
    int e0 = rp[i], e1 = rp[i + 1];
    float di = dinv[i];
    float2 a = __half22float2(Hs[(size_t)i * 32 + sub]);
    for (int e = e0; e < e1; e += 16) {
        float2 v[16];
#pragma unroll
        for (int u = 0; u < 16; u++) {
            int idx = e + u;
            bool ok = idx < e1;
            int s = col[ok ? idx : e0];
            float2 f = __half22float2(Hs[(size_t)s * 32 + sub]);
            v[u].x = ok ? f.x : 0.f;
            v[u].y = ok ? f.y : 0.f;
        }
#pragma unroll
        for (int st = 1; st < 16; st <<= 1)
#pragma unroll
            for (int u = 0; u < 16; u += 2 * st) {
                v[u].x += v[u + st].x;
                v[u].y += v[u + st].y;
            }
        a.x += v[0].x;
        a.y += v[0].y;
    }
    float2 b = reinterpret_cast<const float2*>(bias)[sub];
    float2 o;
    o.x = fmaf(di, a.x, b.x);
    o.y = fmaf(di, a.y, b.y);
    reinterpret_cast<float2*>(out)[(size_t)i * 32 + sub] = o;
}

// ---------------- BN stats over plane-major f16 t ----------------
__global__ __launch_bounds__(256) void k_statsp(const __half2* __restrict__ X2,
                                                float* __restrict__ S, int N) {
    int cp = threadIdx.x & 63;   // global half2 column pair
    int hr = threadIdx.x >> 6;   // 0..3
    int gG = cp >> 3, j = cp & 7;
    const __half2* P = X2 + (size_t)gG * N * 8;
    int rend = min(N, (int)(blockIdx.x + 1) * 256);
    float2 s = make_float2(0.f, 0.f), q = make_float2(0.f, 0.f);
    for (int r = blockIdx.x * 256 + hr; r < rend; r += 4) {
        float2 v = __half22float2(P[(size_t)r * 8 + j]);
        s.x += v.x; s.y += v.y;
        q.x += v.x * v.x; q.y += v.y * v.y;
    }
    __shared__ float ls[4][64][2], lq[4][64][2];
    ls[hr][cp][0] = s.x; ls[hr][cp][1] = s.y;
    lq[hr][cp][0] = q.x; lq[hr][cp][1] = q.y;
    __syncthreads();
    if (hr == 0) {
#pragma unroll
        for (int jj = 1; jj < 4; jj++) {
            s.x += ls[jj][cp][0]; s.y += ls[jj][cp][1];
            q.x += lq[jj][cp][0]; q.y += lq[jj][cp][1];
        }
        atomicAdd(&S[2 * cp], s.x);
        atomicAdd(&S[2 * cp + 1], s.y);
        atomicAdd(&S[128 + 2 * cp], q.x);
        atomicAdd(&S[128 + 2 * cp + 1], q.y);
    }
}

// ---------------- launch ----------------
extern "C" void kernel_launch(void* const* d_in, const int* in_sizes, int n_in,
                              void* d_out, int out_size, void* d_ws, size_t ws_size,
                              hipStream_t stream) {
    const float* x   = (const float*)d_in[0];
    const int*   ew  = (const int*)d_in[1];
    const float* W1  = (const float*)d_in[2];
    const float* b1  = (const float*)d_in[3];
    const float* g1  = (const float*)d_in[4];
    const float* be1 = (const float*)d_in[5];
    const float* W2  = (const float*)d_in[6];
    const float* b2  = (const float*)d_in[7];
    const float* g2  = (const float*)d_in[8];
    const float* be2 = (const float*)d_in[9];
    const float* W3  = (const float*)d_in[10];
    const float* b3  = (const float*)d_in[11];
    const int N = in_sizes[0] / 128;
    const int E = in_sizes[1] / 2;
    const int NB = (N + 255) >> 8;

    char* w = (char*)d_ws;
    size_t off = 0;
    auto alloc = [&](size_t bytes) -> char* {
        char* p = w + off;
        off = (off + bytes + 255) & ~(size_t)255;
        return p;
    };
    int*    col   = (int*)alloc((size_t)E * 4);
    int2*   be    = (int2*)alloc((size_t)E * 8);
    int*    rp    = (int*)alloc((size_t)(N + 1) * 4);
    float*  dinv  = (float*)alloc((size_t)N * 4);
    float*  S1    = (float*)alloc(1024);
    float*  S2    = (float*)alloc(1024);
    int*    flag  = (int*)alloc(256);
    int*    bsize = (int*)alloc(257 * 4);
    int*    bbase = (int*)alloc(257 * 4);
    int*    bcur  = (int*)alloc(257 * 4);
    __half* h     = (__half*)alloc((size_t)N * 128 * 2);
    __half* t     = (__half*)alloc((size_t)N * 128 * 2);
    (void)ws_size; (void)n_in; (void)out_size;

    const int gM = (N + 63) / 64;
    const int gP = 8 * ((N + 31) / 32);
    const int gA8 = (N + 7) / 8;
    const int gS = (N + 255) / 256;
    const int PB = 128;
    const int chunk = (E + PB - 1) / PB;
    const float invN = 1.0f / (float)N;

    k_detect<<<1, 256, 0, stream>>>(ew, flag, bsize);
    k_bhist<<<PB, 256, 0, stream>>>(ew, flag, bsize, E, NB, chunk);
    k_bscan<<<1, 256, 0, stream>>>(bsize, bbase, bcur, NB, S1, S2);
    k_part<<<PB, 256, 0, stream>>>(ew, flag, bcur, be, E, NB, chunk);
    k_bdegfill<<<NB, 256, 0, stream>>>(be, bbase, rp, dinv, col, N, NB);

    // layer 1: x (f32 rows) -> h (planes)
    k_mmf<128, false, true, false, true><<<gM, 256, 0, stream>>>(x, W1, h, dinv, S1, g1, be1, N, invN);
    k_aggp<<<gP, 256, 0, stream>>>(h, rp, col, dinv, b1, t, N);
    k_statsp<<<gS, 256, 0, stream>>>((const __half2*)t, S1, N);

    // layer 2: t (planes) -> h (planes), BN1+ReLU fused
    k_mmf<128, true, false, true, true><<<gM, 256, 0, stream>>>(t, W2, h, dinv, S1, g1, be1, N, invN);
    k_aggp<<<gP, 256, 0, stream>>>(h, rp, col, dinv, b2, t, N);
    k_statsp<<<gS, 256, 0, stream>>>((const __half2*)t, S2, N);

    // layer 3: t (planes) -> h (rows, D=64), BN2+ReLU fused; agg64 -> d_out f32
    k_mmf<64, true, false, true, false><<<gM, 256, 0, stream>>>(t, W3, h, dinv, S2, g2, be2, N, invN);
    k_agg64<<<gA8, 256, 0, stream>>>((const __half2*)h, rp, col, dinv, b3, (float*)d_out, N);
}

// Round 9
// 241.239 us; speedup vs baseline: 1.1403x; 1.1403x over previous
//
#include <hip/hip_runtime.h>
#include <hip/hip_fp16.h>
#include <math.h>

typedef _Float16 half8_t __attribute__((ext_vector_type(8)));
typedef float f32x4 __attribute__((ext_vector_type(4)));

struct __align__(16) h2x4 { __half2 a, b, c, d; };

// Edge access: flag=1 -> int64 storage, flag=0 -> int32.
__device__ inline int edge_src(const int* ew, int f, int e, int E) {
    return f ? ew[2 * e] : ew[e];
}
__device__ inline int edge_dst(const int* ew, int f, int e, int E) {
    return f ? ew[2 * E + 2 * e] : ew[E + e];
}

// ---------------- edge dtype sniff + bsize zero ----------------
__global__ void k_detect(const int* __restrict__ ew, int* __restrict__ flag,
                         int* __restrict__ bsize) {
    __shared__ int nz;
    if (threadIdx.x == 0) nz = 0;
    bsize[threadIdx.x] = 0;
    __syncthreads();
    int a = ew[2 * threadIdx.x + 1];
    int b = ew[512 + 2 * threadIdx.x + 1];
    if (a | b) atomicAdd(&nz, 1);
    __syncthreads();
    if (threadIdx.x == 0) *flag = (nz == 0) ? 1 : 0;
}

// ---------------- bucketed CSR build (buckets of 256 dst nodes, NB<=256) ----------------
__global__ __launch_bounds__(256) void k_bhist(const int* __restrict__ ew,
                                               const int* __restrict__ flag,
                                               int* __restrict__ bsize,
                                               int E, int NB, int chunk) {
    __shared__ int hist[256];
    int t = threadIdx.x;
    hist[t] = 0;
    __syncthreads();
    int f = *flag;
    int c0 = blockIdx.x * chunk, c1 = min(E, c0 + chunk);
    for (int e = c0 + t; e < c1; e += 256)
        atomicAdd(&hist[edge_dst(ew, f, e, E) >> 8], 1);
    __syncthreads();
    if (t < NB && hist[t]) atomicAdd(&bsize[t], hist[t]);
}

// scan bucket sizes; also zero the BN stat accumulators (saves 2 memsets)
__global__ __launch_bounds__(256) void k_bscan(const int* __restrict__ bsize,
                                               int* __restrict__ bbase,
                                               int* __restrict__ bcur, int NB,
                                               float* __restrict__ S1,
                                               float* __restrict__ S2) {
    __shared__ int buf[256];
    int t = threadIdx.x;
    S1[t] = 0.f;
    S2[t] = 0.f;
    int v = (t < NB) ? bsize[t] : 0;
    buf[t] = v;
    __syncthreads();
    int x = v;
    for (int off = 1; off < 256; off <<= 1) {
        int y = (t >= off) ? buf[t - off] : 0;
        __syncthreads();
        x += y;
        buf[t] = x;
        __syncthreads();
    }
    if (t <= NB) {
        int ex = (t < NB) ? (buf[t] - bsize[t]) : buf[NB ? NB - 1 : 0];
        bbase[t] = ex;
        if (t < NB) bcur[t] = ex;
    }
}

__global__ __launch_bounds__(256) void k_part(const int* __restrict__ ew,
                                              const int* __restrict__ flag,
                                              int* __restrict__ bcur,
                                              int2* __restrict__ be,
                                              int E, int NB, int chunk) {
    __shared__ int histL[256], baseL[256];
    int t = threadIdx.x;
    histL[t] = 0;
    __syncthreads();
    int f = *flag;
    int c0 = blockIdx.x * chunk, c1 = min(E, c0 + chunk);
    for (int e = c0 + t; e < c1; e += 256)
        atomicAdd(&histL[edge_dst(ew, f, e, E) >> 8], 1);
    __syncthreads();
    if (t < NB) {
        int h = histL[t];
        baseL[t] = h ? atomicAdd(&bcur[t], h) : 0;
    }
    __syncthreads();
    histL[t] = 0;
    __syncthreads();
    for (int e = c0 + t; e < c1; e += 256) {
        int s = edge_src(ew, f, e, E);
        int d = edge_dst(ew, f, e, E);
        int b = d >> 8;
        int off = baseL[b] + atomicAdd(&histL[b], 1);
        be[off] = make_int2(s, d);
    }
}

// per-bucket: degree count + scan -> rp/dinv, then fill col (merged)
__global__ __launch_bounds__(256) void k_bdegfill(const int2* __restrict__ be,
                                                  const int* __restrict__ bbase,
                                                  int* __restrict__ rp,
                                                  float* __restrict__ dinv,
                                                  int* __restrict__ col,
                                                  int N, int NB) {
    __shared__ int cnt[256];
    __shared__ int buf[256];
    int t = threadIdx.x, b = blockIdx.x;
    cnt[t] = 0;
    __syncthreads();
    int p0 = bbase[b], p1 = bbase[b + 1];
    for (int p = p0 + t; p < p1; p += 256)
        atomicAdd(&cnt[be[p].y & 255], 1);
    __syncthreads();
    int v = cnt[t];
    buf[t] = v;
    __syncthreads();
    int x = v;
    for (int off = 1; off < 256; off <<= 1) {
        int y = (t >= off) ? buf[t - off] : 0;
        __syncthreads();
        x += y;
        buf[t] = x;
        __syncthreads();
    }
    int start = bbase[b] + x - v;   // exclusive prefix within bucket
    int i = (b << 8) + t;
    if (i < N) {
        rp[i] = start;
        dinv[i] = rsqrtf((float)(v + 1));  // +1 self loop
    }
    if (b == NB - 1 && t == 255) rp[N] = bbase[b] + x;  // = E
    __syncthreads();
    cnt[t] = start;                 // becomes write cursor
    __syncthreads();
    for (int p = p0 + t; p < p1; p += 256) {
        int2 e = be[p];
        int pos = atomicAdd(&cnt[e.y & 255], 1);
        col[pos] = e.x;
    }
}

// ------- MFMA matmul: H = fp16( dinv[r] * act(X) @ W ), W f32->f16 staged in LDS -------
template <int D, bool FUSE, bool XF32>
__global__ __launch_bounds__(256) void k_mmf(const void* __restrict__ Xv,
                                             const float* __restrict__ W,
                                             __half* __restrict__ H,
                                             const float* __restrict__ dinv,
                                             const float* __restrict__ S,
                                             const float* __restrict__ g,
                                             const float* __restrict__ be_,
                                             int N, float invN) {
    constexpr int NF = D / 16;
    __shared__ _Float16 sW[4][NF][4][16][8];
    __shared__ float sAl[128], sBe[128];
    const int t = threadIdx.x;
    if (FUSE && t < 128) {
        float m = S[t] * invN;
        float var = fmaf(-m, m, S[128 + t] * invN);
        float al = g[t] * rsqrtf(var + 1e-5f);
        sAl[t] = al;
        sBe[t] = fmaf(-m, al, be_[t]);
    }
    for (int idx = t; idx < 128 * D / 4; idx += 256) {
        int k = idx / (D / 4);
        int n4 = (idx % (D / 4)) * 4;
        float4 w4 = reinterpret_cast<const float4*>(W)[idx];
        int kb = k >> 5, kg = (k >> 3) & 3, j = k & 7;
        const float* wp = &w4.x;
#pragma unroll
        for (int jj = 0; jj < 4; jj++) {
            int n = n4 + jj;
            sW[kb][n >> 4][kg][n & 15][j] = (_Float16)wp[jj];
        }
    }
    __syncthreads();

    const int l = t & 63;
    const int w = t >> 6;
    const int row_base = blockIdx.x * 64 + w * 16;
    const int m16 = l & 15, kg = l >> 4;

    f32x4 acc[NF];
#pragma unroll
    for (int nf = 0; nf < NF; nf++) acc[nf] = (f32x4){0.f, 0.f, 0.f, 0.f};

    int ra = row_base + m16;
    if (ra > N - 1) ra = N - 1;

#pragma unroll
    for (int kb = 0; kb < 4; kb++) {
        int kbase = kb * 32 + kg * 8;
        half8_t a;
        if (XF32) {
            const float* Xf = (const float*)Xv;
            float4 x0 = reinterpret_cast<const float4*>(Xf + (size_t)ra * 128 + kbase)[0];
            float4 x1 = reinterpret_cast<const float4*>(Xf + (size_t)ra * 128 + kbase)[1];
            a[0] = (_Float16)x0.x; a[1] = (_Float16)x0.y;
            a[2] = (_Float16)x0.z; a[3] = (_Float16)x0.w;
            a[4] = (_Float16)x1.x; a[5] = (_Float16)x1.y;
            a[6] = (_Float16)x1.z; a[7] = (_Float16)x1.w;
        } else {
            const __half* Xh = (const __half*)Xv;
            a = *reinterpret_cast<const half8_t*>(Xh + (size_t)ra * 128 + kbase);
            if (FUSE) {
                float4 al0 = *reinterpret_cast<const float4*>(&sAl[kbase]);
                float4 al1 = *reinterpret_cast<const float4*>(&sAl[kbase + 4]);
                float4 be0 = *reinterpret_cast<const float4*>(&sBe[kbase]);
                float4 be1 = *reinterpret_cast<const float4*>(&sBe[kbase + 4]);
                const float* alp0 = &al0.x; const float* alp1 = &al1.x;
                const float* bep0 = &be0.x; const float* bep1 = &be1.x;
#pragma unroll
                for (int j = 0; j < 4; j++)
                    a[j] = (_Float16)fmaxf(0.f, fmaf(alp0[j], (float)a[j], bep0[j]));
#pragma unroll
                for (int j = 0; j < 4; j++)
                    a[4 + j] = (_Float16)fmaxf(0.f, fmaf(alp1[j], (float)a[4 + j], bep1[j]));
            }
        }
#pragma unroll
        for (int nf = 0; nf < NF; nf++) {
            half8_t b = *reinterpret_cast<const half8_t*>(&sW[kb][nf][kg][m16][0]);
            acc[nf] = __builtin_amdgcn_mfma_f32_16x16x32_f16(a, b, acc[nf], 0, 0, 0);
        }
    }

    float dv[4];
    int rbase = row_base + kg * 4;
#pragma unroll
    for (int r = 0; r < 4; r++)
        dv[r] = (rbase + r < N) ? dinv[rbase + r] : 0.f;
#pragma unroll
    for (int nf = 0; nf < NF; nf++) {
#pragma unroll
        for (int r = 0; r < 4; r++) {
            int gr = rbase + r;
            if (gr < N)
                H[(size_t)gr * D + nf * 16 + m16] = __float2half(acc[nf][r] * dv[r]);
        }
    }
}

// ------- agg D=128: wave/node; 16 lanes x 16B cover one edge row; 4 slots x 4 batches -------
__global__ __launch_bounds__(256) void k_agg128(const __half* __restrict__ Hs,
                                                const int* __restrict__ rp,
                                                const int* __restrict__ col,
                                                const float* __restrict__ dinv,
                                                const float* __restrict__ bias,
                                                __half* __restrict__ out, int N) {
    const int wv = threadIdx.x >> 6, lane = threadIdx.x & 63;
    const int i = blockIdx.x * 4 + wv;
    if (i >= N) return;
    const int u = lane >> 4;      // edge slot 0..3
    const int fb = lane & 15;     // 16B feature block
    const int e0 = rp[i], e1 = rp[i + 1];
    float acc[8];
#pragma unroll
    for (int p = 0; p < 8; p++) acc[p] = 0.f;

    for (int e = e0; e < e1; e += 16) {
        int4 raw[4];
#pragma unroll
        for (int b = 0; b < 4; b++) {
            int idx = e + 4 * b + u;
            bool ok = idx < e1;
            int s = col[ok ? idx : e0];
            int4 r = *reinterpret_cast<const int4*>(Hs + (size_t)s * 128 + fb * 8);
            raw[b].x = ok ? r.x : 0;
            raw[b].y = ok ? r.y : 0;
            raw[b].z = ok ? r.z : 0;
            raw[b].w = ok ? r.w : 0;
        }
#pragma unroll
        for (int b = 0; b < 4; b++) {
            const __half2* hp = reinterpret_cast<const __half2*>(&raw[b]);
#pragma unroll
            for (int p = 0; p < 4; p++) {
                float2 f = __half22float2(hp[p]);
                acc[2 * p]     += f.x;
                acc[2 * p + 1] += f.y;
            }
        }
    }
    // reduce across the 4 edge slots
#pragma unroll
    for (int off = 16; off < 64; off <<= 1)
#pragma unroll
        for (int p = 0; p < 8; p++)
            acc[p] += __shfl_xor(acc[p], off);

    if (u == 0) {
        float di = dinv[i];
        const __half2* sp = reinterpret_cast<const __half2*>(Hs + (size_t)i * 128 + fb * 8);
        __half2 o[4];
#pragma unroll
        for (int p = 0; p < 4; p++) {
            float2 sf = __half22float2(sp[p]);
            float bx = bias[fb * 8 + 2 * p];
            float by = bias[fb * 8 + 2 * p + 1];
            o[p] = __floats2half2_rn(fmaf(di, acc[2 * p] + sf.x, bx),
                                     fmaf(di, acc[2 * p + 1] + sf.y, by));
        }
        *reinterpret_cast<int4*>(out + (size_t)i * 128 + fb * 8) = *reinterpret_cast<const int4*>(o);
    }
}

// ------- agg D=64: wave/node; 8 lanes x 16B per edge row; 8 slots x 2 batches; f32 out -------
__global__ __launch_bounds__(256) void k_agg64(const __half* __restrict__ Hs,
                                               const int* __restrict__ rp,
                                               const int* __restrict__ col,
                                               const float* __restrict__ dinv,
                                               const float* __restrict__ bias,
                                               float* __restrict__ out, int N) {
    const int wv = threadIdx.x >> 6, lane = threadIdx.x & 63;
    const int i = blockIdx.x * 4 + wv;
    if (i >= N) return;
    const int u = lane >> 3;      // edge slot 0..7
    const int fb = lane & 7;      // 16B feature block
    const int e0 = rp[i], e1 = rp[i + 1];
    float acc[8];
#pragma unroll
    for (int p = 0; p < 8; p++) acc[p] = 0.f;

    for (int e = e0; e < e1; e += 16) {
        int4 raw[2];
#pragma unroll
        for (int b = 0; b < 2; b++) {
            int idx = e + 8 * b + u;
            bool ok = idx < e1;
            int s = col[ok ? idx : e0];
            int4 r = *reinterpret_cast<const int4*>(Hs + (size_t)s * 64 + fb * 8);
            raw[b].x = ok ? r.x : 0;
            raw[b].y = ok ? r.y : 0;
            raw[b].z = ok ? r.z : 0;
            raw[b].w = ok ? r.w : 0;
        }
#pragma unroll
        for (int b = 0; b < 2; b++) {
            const __half2* hp = reinterpret_cast<const __half2*>(&raw[b]);
#pragma unroll
            for (int p = 0; p < 4; p++) {
                float2 f = __half22float2(hp[p]);
                acc[2 * p]     += f.x;
                acc[2 * p + 1] += f.y;
            }
        }
    }
    // reduce across the 8 edge slots
#pragma unroll
    for (int off = 8; off < 64; off <<= 1)
#pragma unroll
        for (int p = 0; p < 8; p++)
            acc[p] += __shfl_xor(acc[p], off);

    if (u == 0) {
        float di = dinv[i];
        const __half2* sp = reinterpret_cast<const __half2*>(Hs + (size_t)i * 64 + fb * 8);
        float4 o0, o1;
        float* op0 = &o0.x;
        float* op1 = &o1.x;
#pragma unroll
        for (int p = 0; p < 4; p++) {
            float2 sf = __half22float2(sp[p]);
            float r0 = fmaf(di, acc[2 * p] + sf.x, bias[fb * 8 + 2 * p]);
            float r1 = fmaf(di, acc[2 * p + 1] + sf.y, bias[fb * 8 + 2 * p + 1]);
            if (p < 2) { op0[2 * p] = r0; op0[2 * p + 1] = r1; }
            else       { op1[2 * (p - 2)] = r0; op1[2 * (p - 2) + 1] = r1; }
        }
        float4* dst = reinterpret_cast<float4*>(out + (size_t)i * 64 + fb * 8);
        dst[0] = o0;
        dst[1] = o1;
    }
}

// ---------------- BN stats over f16 t (row-major) ----------------
__global__ __launch_bounds__(256) void k_stats(const __half2* __restrict__ X2,
                                               float* __restrict__ S, int N) {
    int cp = threadIdx.x & 63;
    int hr = threadIdx.x >> 6;
    int rend = min(N, (int)(blockIdx.x + 1) * 256);
    float2 s = make_float2(0.f, 0.f), q = make_float2(0.f, 0.f);
    for (int r = blockIdx.x * 256 + hr; r < rend; r += 4) {
        float2 v = __half22float2(X2[(size_t)r * 64 + cp]);
        s.x += v.x; s.y += v.y;
        q.x += v.x * v.x; q.y += v.y * v.y;
    }
    __shared__ float ls[4][64][2], lq[4][64][2];
    ls[hr][cp][0] = s.x; ls[hr][cp][1] = s.y;
    lq[hr][cp][0] = q.x; lq[hr][cp][1] = q.y;
    __syncthreads();
    if (hr == 0) {
#pragma unroll
        for (int j = 1; j < 4; j++) {
            s.x += ls[j][cp][0]; s.y += ls[j][cp][1];
            q.x += lq[j][cp][0]; q.y += lq[j][cp][1];
        }
        atomicAdd(&S[2 * cp], s.x);
        atomicAdd(&S[2 * cp + 1], s.y);
        atomicAdd(&S[128 + 2 * cp], q.x);
        atomicAdd(&S[128 + 2 * cp + 1], q.y);
    }
}

// ---------------- launch ----------------
extern "C" void kernel_launch(void* const* d_in, const int* in_sizes, int n_in,
                              void* d_out, int out_size, void* d_ws, size_t ws_size,
                              hipStream_t stream) {
    const float* x   = (const float*)d_in[0];
    const int*   ew  = (const int*)d_in[1];
    const float* W1  = (const float*)d_in[2];
    const float* b1  = (const float*)d_in[3];
    const float* g1  = (const float*)d_in[4];
    const float* be1 = (const float*)d_in[5];
    const float* W2  = (const float*)d_in[6];
    const float* b2  = (const float*)d_in[7];
    const float* g2  = (const float*)d_in[8];
    const float* be2 = (const float*)d_in[9];
    const float* W3  = (const float*)d_in[10];
    const float* b3  = (const float*)d_in[11];
    const int N = in_sizes[0] / 128;
    const int E = in_sizes[1] / 2;
    const int NB = (N + 255) >> 8;

    char* w = (char*)d_ws;
    size_t off = 0;
    auto alloc = [&](size_t bytes) -> char* {
        char* p = w + off;
        off = (off + bytes + 255) & ~(size_t)255;
        return p;
    };
    int*    col   = (int*)alloc((size_t)E * 4);
    int2*   be    = (int2*)alloc((size_t)E * 8);
    int*    rp    = (int*)alloc((size_t)(N + 1) * 4);
    float*  dinv  = (float*)alloc((size_t)N * 4);
    float*  S1    = (float*)alloc(1024);
    float*  S2    = (float*)alloc(1024);
    int*    flag  = (int*)alloc(256);
    int*    bsize = (int*)alloc(257 * 4);
    int*    bbase = (int*)alloc(257 * 4);
    int*    bcur  = (int*)alloc(257 * 4);
    __half* h     = (__half*)alloc((size_t)N * 128 * 2);
    __half* t     = (__half*)alloc((size_t)N * 128 * 2);
    (void)ws_size; (void)n_in; (void)out_size;

    const int gM = (N + 63) / 64;
    const int gA = (N + 3) / 4;
    const int gS = (N + 255) / 256;
    const int PB = 128;
    const int chunk = (E + PB - 1) / PB;
    const float invN = 1.0f / (float)N;

    k_detect<<<1, 256, 0, stream>>>(ew, flag, bsize);
    k_bhist<<<PB, 256, 0, stream>>>(ew, flag, bsize, E, NB, chunk);
    k_bscan<<<1, 256, 0, stream>>>(bsize, bbase, bcur, NB, S1, S2);
    k_part<<<PB, 256, 0, stream>>>(ew, flag, bcur, be, E, NB, chunk);
    k_bdegfill<<<NB, 256, 0, stream>>>(be, bbase, rp, dinv, col, N, NB);

    // layer 1
    k_mmf<128, false, true><<<gM, 256, 0, stream>>>(x, W1, h, dinv, S1, g1, be1, N, invN);
    k_agg128<<<gA, 256, 0, stream>>>(h, rp, col, dinv, b1, t, N);
    k_stats<<<gS, 256, 0, stream>>>((const __half2*)t, S1, N);

    // layer 2 (BN1+ReLU fused into A-fragment load)
    k_mmf<128, true, false><<<gM, 256, 0, stream>>>(t, W2, h, dinv, S1, g1, be1, N, invN);
    k_agg128<<<gA, 256, 0, stream>>>(h, rp, col, dinv, b2, t, N);
    k_stats<<<gS, 256, 0, stream>>>((const __half2*)t, S2, N);

    // layer 3 (BN2+ReLU fused, D_OUT = 64, straight to d_out)
    k_mmf<64, true, false><<<gM, 256, 0, stream>>>(t, W3, h, dinv, S2, g2, be2, N, invN);
    k_agg64<<<gA, 256, 0, stream>>>(h, rp, col, dinv, b3, (float*)d_out, N);
}